// Round 1
// baseline (728.487 us; speedup 1.0000x reference)
//
#include <hip/hip_runtime.h>
#include <hip/hip_bf16.h>

// Problem constants (from reference): N=100000 nodes, D=64 feat, H=256 hidden, E=1000000 edges.
#define N_NODES 100000
#define DIM 64
#define HID 256
#define E_EDGES 1000000
#define NODES_PER_BLOCK 8
#define MLP_BLOCKS (N_NODES / NODES_PER_BLOCK)  // 12500

__device__ __forceinline__ float tanh_fast(float x) {
    // tanh via hw exp; clamp avoids inf/inf NaN. |err| ~1e-6, fine vs 0.118 threshold.
    x = fminf(fmaxf(x, -15.0f), 15.0f);
    float e = __expf(2.0f * x);
    return (e - 1.0f) / (e + 1.0f);
}

// One wave (64 lanes) per edge; lane = feature dim (D==64 exactly).
__global__ void scatter_geo_kernel(const float* __restrict__ feat,
                                   const int* __restrict__ src,
                                   const int* __restrict__ dst,
                                   float* __restrict__ geo_sum,
                                   float* __restrict__ cnt) {
    int e = blockIdx.x * 4 + (threadIdx.x >> 6);
    int lane = threadIdx.x & 63;
    int s = src[e];
    int d = dst[e];
    float v = feat[s * DIM + lane];
    atomicAdd(&geo_sum[d * DIM + lane], v);
    if (lane == 0) atomicAdd(&cnt[d], 1.0f);
}

__global__ void scatter_trans_kernel(const float* __restrict__ feat,
                                     const int* __restrict__ src,
                                     const int* __restrict__ dst,
                                     const float* __restrict__ w,
                                     float* __restrict__ trans) {
    int e = blockIdx.x * 4 + (threadIdx.x >> 6);
    int lane = threadIdx.x & 63;
    int s = src[e];
    int d = dst[e];
    float we = w[e];
    float v = feat[s * DIM + lane] * we;
    atomicAdd(&trans[d * DIM + lane], v);
}

// Semantic-attention MLP: per block, A = z rows (8 nodes x 2 views = 16 rows) x K=64,
// B = W1 (64 x 256). 4x4 register tile per thread; z in LDS (broadcast float4 reads),
// W1 rows streamed as float4 from L2. Emits per-block partial sums of h@W2 per view k.
__global__ void mlp_kernel(const float* __restrict__ geo_raw,   // raw sums (d_out)
                           const float* __restrict__ trans,
                           const float* __restrict__ cnt,
                           const float* __restrict__ W1,
                           const float* __restrict__ b1,
                           const float* __restrict__ W2,
                           float* __restrict__ partials) {
    // stride 20 floats: keeps float4 rows 16B-aligned, write conflicts 8-way not 32-way
    __shared__ float z_lds[DIM][20];
    __shared__ float wred[4][2];

    int t = threadIdx.x;           // 0..255
    int d = t & 63;
    int nlb = t >> 6;              // 0..3
    int node0 = blockIdx.x * NODES_PER_BLOCK;

    // Stage z = [geo_mean | trans] into LDS, i = nl*2 + k (row index), d-major.
    #pragma unroll
    for (int rep = 0; rep < 2; ++rep) {
        int nl = nlb * 2 + rep;    // 0..7
        int node = node0 + nl;
        float c = fmaxf(cnt[node], 1.0f);
        float g = geo_raw[node * DIM + d] * (1.0f / c);  // cnt==0 => sum==0 => 0
        float tr = trans[node * DIM + d];
        z_lds[d][nl * 2 + 0] = g;
        z_lds[d][nl * 2 + 1] = tr;
    }
    __syncthreads();

    int j0 = (t & 63) << 2;        // column base 0..252
    int i0 = (t >> 6) << 2;        // row base 0,4,8,12 (uniform per wave -> LDS broadcast)

    float acc[4][4];
    #pragma unroll
    for (int a = 0; a < 4; ++a)
        #pragma unroll
        for (int b = 0; b < 4; ++b) acc[a][b] = 0.0f;

    #pragma unroll 8
    for (int dd = 0; dd < DIM; ++dd) {
        float4 zv = *(const float4*)&z_lds[dd][i0];
        float4 wv = *(const float4*)&W1[dd * HID + j0];
        acc[0][0] += zv.x * wv.x; acc[0][1] += zv.x * wv.y; acc[0][2] += zv.x * wv.z; acc[0][3] += zv.x * wv.w;
        acc[1][0] += zv.y * wv.x; acc[1][1] += zv.y * wv.y; acc[1][2] += zv.y * wv.z; acc[1][3] += zv.y * wv.w;
        acc[2][0] += zv.z * wv.x; acc[2][1] += zv.z * wv.y; acc[2][2] += zv.z * wv.z; acc[2][3] += zv.z * wv.w;
        acc[3][0] += zv.w * wv.x; acc[3][1] += zv.w * wv.y; acc[3][2] += zv.w * wv.z; acc[3][3] += zv.w * wv.w;
    }

    // Epilogue: tanh, dot with W2, split by view k = row parity (i = nl*2 + k).
    float c0 = 0.0f, c1 = 0.0f;
    #pragma unroll
    for (int jj = 0; jj < 4; ++jj) {
        int j = j0 + jj;
        float bj = b1[j];
        float w2j = W2[j];
        #pragma unroll
        for (int ii = 0; ii < 4; ++ii) {
            float h = tanh_fast(acc[ii][jj] + bj);
            if ((ii & 1) == 0) c0 += h * w2j;   // i0 is even, so parity == ii&1
            else               c1 += h * w2j;
        }
    }

    // Block reduction -> per-block partials (no global atomic contention).
    #pragma unroll
    for (int off = 32; off > 0; off >>= 1) {
        c0 += __shfl_down(c0, off);
        c1 += __shfl_down(c1, off);
    }
    int lane = t & 63, wv = t >> 6;
    if (lane == 0) { wred[wv][0] = c0; wred[wv][1] = c1; }
    __syncthreads();
    if (t == 0) {
        float p0 = wred[0][0] + wred[1][0] + wred[2][0] + wred[3][0];
        float p1 = wred[0][1] + wred[1][1] + wred[2][1] + wred[3][1];
        partials[blockIdx.x * 2 + 0] = p0;
        partials[blockIdx.x * 2 + 1] = p1;
    }
}

// Single block: reduce per-block partials, compute softmax beta over the 2 views.
__global__ void beta_kernel(const float* __restrict__ partials, float* __restrict__ beta) {
    __shared__ float wred[4][2];
    int t = threadIdx.x;
    float c0 = 0.0f, c1 = 0.0f;
    for (int i = t; i < MLP_BLOCKS; i += 256) {
        c0 += partials[i * 2 + 0];
        c1 += partials[i * 2 + 1];
    }
    #pragma unroll
    for (int off = 32; off > 0; off >>= 1) {
        c0 += __shfl_down(c0, off);
        c1 += __shfl_down(c1, off);
    }
    int lane = t & 63, wv = t >> 6;
    if (lane == 0) { wred[wv][0] = c0; wred[wv][1] = c1; }
    __syncthreads();
    if (t == 0) {
        float s0 = (wred[0][0] + wred[1][0] + wred[2][0] + wred[3][0]) / (float)N_NODES;
        float s1 = (wred[0][1] + wred[1][1] + wred[2][1] + wred[3][1]) / (float)N_NODES;
        float m = fmaxf(s0, s1);
        float e0 = __expf(s0 - m), e1 = __expf(s1 - m);
        float inv = 1.0f / (e0 + e1);
        beta[0] = e0 * inv;
        beta[1] = e1 * inv;
    }
}

// out = beta0 * geo_mean + beta1 * trans  (geo raw sums live in d_out; in-place).
__global__ void combine_kernel(float* __restrict__ out_geo,
                               const float* __restrict__ trans,
                               const float* __restrict__ cnt,
                               const float* __restrict__ beta) {
    int gid = blockIdx.x * 256 + threadIdx.x;   // one float4 per thread
    int node = gid >> 4;                        // 16 float4 per node
    float invc = 1.0f / fmaxf(cnt[node], 1.0f);
    float b0 = beta[0] * invc;
    float b1 = beta[1];
    float4 g = ((const float4*)out_geo)[gid];
    float4 tr = ((const float4*)trans)[gid];
    float4 o;
    o.x = b0 * g.x + b1 * tr.x;
    o.y = b0 * g.y + b1 * tr.y;
    o.z = b0 * g.z + b1 * tr.z;
    o.w = b0 * g.w + b1 * tr.w;
    ((float4*)out_geo)[gid] = o;
}

extern "C" void kernel_launch(void* const* d_in, const int* in_sizes, int n_in,
                              void* d_out, int out_size, void* d_ws, size_t ws_size,
                              hipStream_t stream) {
    const float* loc_feat = (const float*)d_in[0];
    const int* geo_src    = (const int*)d_in[1];
    const int* geo_dst    = (const int*)d_in[2];
    const int* trans_src  = (const int*)d_in[3];
    const int* trans_dst  = (const int*)d_in[4];
    const float* trans_w  = (const float*)d_in[5];
    const float* W1       = (const float*)d_in[6];
    const float* b1       = (const float*)d_in[7];
    const float* W2       = (const float*)d_in[8];
    float* out = (float*)d_out;

    // Workspace layout (floats): [trans N*D][cnt N][partials MLP_BLOCKS*2][beta 2]
    float* trans    = (float*)d_ws;
    float* cnt      = trans + (size_t)N_NODES * DIM;
    float* partials = cnt + N_NODES;
    float* beta     = partials + MLP_BLOCKS * 2;

    // Zero accumulators (d_out = geo sums; ws re-poisoned each call).
    hipMemsetAsync(d_out, 0, (size_t)N_NODES * DIM * sizeof(float), stream);
    hipMemsetAsync(d_ws, 0, ((size_t)N_NODES * DIM + N_NODES) * sizeof(float), stream);

    // Edge scatter: wave per edge, lane per feature dim.
    scatter_geo_kernel<<<E_EDGES / 4, 256, 0, stream>>>(loc_feat, geo_src, geo_dst, out, cnt);
    scatter_trans_kernel<<<E_EDGES / 4, 256, 0, stream>>>(loc_feat, trans_src, trans_dst, trans_w, trans);

    // Semantic-attention MLP -> per-block partials.
    mlp_kernel<<<MLP_BLOCKS, 256, 0, stream>>>(out, trans, cnt, W1, b1, W2, partials);

    // Reduce partials, softmax -> beta.
    beta_kernel<<<1, 256, 0, stream>>>(partials, beta);

    // Final weighted combine (in-place on d_out).
    combine_kernel<<<(N_NODES * DIM / 4) / 256, 256, 0, stream>>>(out, trans, cnt, beta);
}

// Round 2
// 648.146 us; speedup vs baseline: 1.1240x; 1.1240x over previous
//
#include <hip/hip_runtime.h>
#include <hip/hip_bf16.h>

// N=100000 nodes, D=64 feat, H=256 hidden, E=1000000 edges per relation.
#define N_NODES 100000
#define DIM 64
#define HID 256
#define E_EDGES 1000000
#define TWO_N (2 * N_NODES)
#define NODES_PER_BLOCK 8
#define MLP_BLOCKS (N_NODES / NODES_PER_BLOCK)      // 12500
#define SCAN_BLOCKS ((TWO_N + 255) / 256)           // 782

__device__ __forceinline__ float tanh_fast(float x) {
    x = fminf(fmaxf(x, -15.0f), 15.0f);
    float e = __expf(2.0f * x);
    return (e - 1.0f) / (e + 1.0f);
}

// ---------- CSR build (counting sort by dst, both relations concatenated) ----------

// cnt2[0..N) = geo in-degree, cnt2[N..2N) = trans in-degree.
__global__ void hist_kernel(const int* __restrict__ gd, const int* __restrict__ td,
                            int* __restrict__ cnt2) {
    int i = blockIdx.x * 256 + threadIdx.x;
    if (i < E_EDGES) atomicAdd(&cnt2[gd[i]], 1);
    else if (i < 2 * E_EDGES) atomicAdd(&cnt2[N_NODES + td[i - E_EDGES]], 1);
}

// Exclusive scan of cnt2 -> off2, 3 passes. Pass 1: per-block scan + block sums.
__global__ void scan1_kernel(const int* __restrict__ cnt2, int* __restrict__ off2,
                             int* __restrict__ bsum) {
    __shared__ int s[256];
    int t = threadIdx.x, gid = blockIdx.x * 256 + t;
    int c = (gid < TWO_N) ? cnt2[gid] : 0;
    s[t] = c;
    __syncthreads();
    int v = c;
    #pragma unroll
    for (int off = 1; off < 256; off <<= 1) {
        int add = (t >= off) ? s[t - off] : 0;
        __syncthreads();
        v += add; s[t] = v;
        __syncthreads();
    }
    if (gid < TWO_N) off2[gid] = v - c;     // block-local exclusive
    if (t == 255) bsum[blockIdx.x] = v;     // block total
}

// Pass 2: single block, exclusive scan of the 782 block sums (carry across chunks).
__global__ void scan2_kernel(int* __restrict__ bsum) {
    __shared__ int s[256];
    int t = threadIdx.x;
    int carry = 0;
    for (int base = 0; base < SCAN_BLOCKS; base += 256) {
        int idx = base + t;
        int c = (idx < SCAN_BLOCKS) ? bsum[idx] : 0;
        s[t] = c;
        __syncthreads();
        int v = c;
        #pragma unroll
        for (int off = 1; off < 256; off <<= 1) {
            int add = (t >= off) ? s[t - off] : 0;
            __syncthreads();
            v += add; s[t] = v;
            __syncthreads();
        }
        if (idx < SCAN_BLOCKS) bsum[idx] = v - c + carry;
        carry += s[255];
        __syncthreads();
    }
}

// Pass 3: add scanned block sums.
__global__ void scan3_kernel(int* __restrict__ off2, const int* __restrict__ bsum) {
    int gid = blockIdx.x * 256 + threadIdx.x;
    if (gid < TWO_N) off2[gid] += bsum[blockIdx.x];
}

// Fill sorted edge arrays. off2 is consumed as cursors (post-fill: off2[i] = end offset;
// gather recovers base = end - cnt2[i]).
__global__ void fill_kernel(const int* __restrict__ gs, const int* __restrict__ gd,
                            const int* __restrict__ td,
                            int* __restrict__ off2,
                            int* __restrict__ geo_srcs, int* __restrict__ trans_eid) {
    int i = blockIdx.x * 256 + threadIdx.x;
    if (i < E_EDGES) {
        int p = atomicAdd(&off2[gd[i]], 1);
        geo_srcs[p] = gs[i];
    } else if (i < 2 * E_EDGES) {
        int e = i - E_EDGES;
        int p = atomicAdd(&off2[N_NODES + td[e]], 1);
        trans_eid[p - E_EDGES] = e;     // trans region starts at global offset E
    }
}

// ---------- Gather-reduce: one wave per (node, relation); lane = feature dim ----------
__global__ void gather_kernel(const float* __restrict__ feat,
                              const int* __restrict__ cnt2, const int* __restrict__ off2,
                              const int* __restrict__ geo_srcs, const int* __restrict__ trans_eid,
                              const int* __restrict__ trans_src, const float* __restrict__ trans_w,
                              float* __restrict__ out_geo, float* __restrict__ trans_out) {
    int wave = blockIdx.x * 4 + (threadIdx.x >> 6);   // 0..2N-1
    int lane = threadIdx.x & 63;
    int deg = cnt2[wave];
    int end = off2[wave];                              // post-fill = end offset
    int base = end - deg;
    float acc = 0.0f;
    if (wave < N_NODES) {
        int k = 0;
        for (; k + 1 < deg; k += 2) {                  // unroll-2: 2 independent feat loads in flight
            int s0 = geo_srcs[base + k];
            int s1 = geo_srcs[base + k + 1];
            float v0 = feat[s0 * DIM + lane];
            float v1 = feat[s1 * DIM + lane];
            acc += v0 + v1;
        }
        if (k < deg) acc += feat[geo_srcs[base + k] * DIM + lane];
        out_geo[wave * DIM + lane] = acc;              // raw sum; mean applied downstream
    } else {
        int b2 = base - E_EDGES;
        int k = 0;
        for (; k + 1 < deg; k += 2) {
            int e0 = trans_eid[b2 + k];
            int e1 = trans_eid[b2 + k + 1];
            int s0 = trans_src[e0], s1 = trans_src[e1];
            float w0 = trans_w[e0], w1 = trans_w[e1];
            acc += feat[s0 * DIM + lane] * w0;
            acc += feat[s1 * DIM + lane] * w1;
        }
        if (k < deg) {
            int e = trans_eid[b2 + k];
            acc += feat[trans_src[e] * DIM + lane] * trans_w[e];
        }
        trans_out[(wave - N_NODES) * DIM + lane] = acc;
    }
}

// ---------- Semantic-attention MLP (unchanged structure; cnt now int) ----------
__global__ void mlp_kernel(const float* __restrict__ geo_raw,
                           const float* __restrict__ trans,
                           const int* __restrict__ cnt,
                           const float* __restrict__ W1,
                           const float* __restrict__ b1,
                           const float* __restrict__ W2,
                           float* __restrict__ partials) {
    __shared__ float z_lds[DIM][20];
    __shared__ float wred[4][2];

    int t = threadIdx.x;
    int d = t & 63;
    int nlb = t >> 6;
    int node0 = blockIdx.x * NODES_PER_BLOCK;

    #pragma unroll
    for (int rep = 0; rep < 2; ++rep) {
        int nl = nlb * 2 + rep;
        int node = node0 + nl;
        float c = fmaxf((float)cnt[node], 1.0f);
        float g = geo_raw[node * DIM + d] * (1.0f / c);
        float tr = trans[node * DIM + d];
        z_lds[d][nl * 2 + 0] = g;
        z_lds[d][nl * 2 + 1] = tr;
    }
    __syncthreads();

    int j0 = (t & 63) << 2;
    int i0 = (t >> 6) << 2;

    float acc[4][4];
    #pragma unroll
    for (int a = 0; a < 4; ++a)
        #pragma unroll
        for (int b = 0; b < 4; ++b) acc[a][b] = 0.0f;

    #pragma unroll 8
    for (int dd = 0; dd < DIM; ++dd) {
        float4 zv = *(const float4*)&z_lds[dd][i0];
        float4 wv = *(const float4*)&W1[dd * HID + j0];
        acc[0][0] += zv.x * wv.x; acc[0][1] += zv.x * wv.y; acc[0][2] += zv.x * wv.z; acc[0][3] += zv.x * wv.w;
        acc[1][0] += zv.y * wv.x; acc[1][1] += zv.y * wv.y; acc[1][2] += zv.y * wv.z; acc[1][3] += zv.y * wv.w;
        acc[2][0] += zv.z * wv.x; acc[2][1] += zv.z * wv.y; acc[2][2] += zv.z * wv.z; acc[2][3] += zv.z * wv.w;
        acc[3][0] += zv.w * wv.x; acc[3][1] += zv.w * wv.y; acc[3][2] += zv.w * wv.z; acc[3][3] += zv.w * wv.w;
    }

    float c0 = 0.0f, c1 = 0.0f;
    #pragma unroll
    for (int jj = 0; jj < 4; ++jj) {
        int j = j0 + jj;
        float bj = b1[j];
        float w2j = W2[j];
        #pragma unroll
        for (int ii = 0; ii < 4; ++ii) {
            float h = tanh_fast(acc[ii][jj] + bj);
            if ((ii & 1) == 0) c0 += h * w2j;
            else               c1 += h * w2j;
        }
    }

    #pragma unroll
    for (int off = 32; off > 0; off >>= 1) {
        c0 += __shfl_down(c0, off);
        c1 += __shfl_down(c1, off);
    }
    int lane = t & 63, wv = t >> 6;
    if (lane == 0) { wred[wv][0] = c0; wred[wv][1] = c1; }
    __syncthreads();
    if (t == 0) {
        partials[blockIdx.x * 2 + 0] = wred[0][0] + wred[1][0] + wred[2][0] + wred[3][0];
        partials[blockIdx.x * 2 + 1] = wred[0][1] + wred[1][1] + wred[2][1] + wred[3][1];
    }
}

__global__ void beta_kernel(const float* __restrict__ partials, float* __restrict__ beta) {
    __shared__ float wred[4][2];
    int t = threadIdx.x;
    float c0 = 0.0f, c1 = 0.0f;
    for (int i = t; i < MLP_BLOCKS; i += 256) {
        c0 += partials[i * 2 + 0];
        c1 += partials[i * 2 + 1];
    }
    #pragma unroll
    for (int off = 32; off > 0; off >>= 1) {
        c0 += __shfl_down(c0, off);
        c1 += __shfl_down(c1, off);
    }
    int lane = t & 63, wv = t >> 6;
    if (lane == 0) { wred[wv][0] = c0; wred[wv][1] = c1; }
    __syncthreads();
    if (t == 0) {
        float s0 = (wred[0][0] + wred[1][0] + wred[2][0] + wred[3][0]) / (float)N_NODES;
        float s1 = (wred[0][1] + wred[1][1] + wred[2][1] + wred[3][1]) / (float)N_NODES;
        float m = fmaxf(s0, s1);
        float e0 = __expf(s0 - m), e1 = __expf(s1 - m);
        float inv = 1.0f / (e0 + e1);
        beta[0] = e0 * inv;
        beta[1] = e1 * inv;
    }
}

__global__ void combine_kernel(float* __restrict__ out_geo,
                               const float* __restrict__ trans,
                               const int* __restrict__ cnt,
                               const float* __restrict__ beta) {
    int gid = blockIdx.x * 256 + threadIdx.x;   // one float4 per thread
    int node = gid >> 4;
    float invc = 1.0f / fmaxf((float)cnt[node], 1.0f);
    float b0 = beta[0] * invc;
    float b1 = beta[1];
    float4 g = ((const float4*)out_geo)[gid];
    float4 tr = ((const float4*)trans)[gid];
    float4 o;
    o.x = b0 * g.x + b1 * tr.x;
    o.y = b0 * g.y + b1 * tr.y;
    o.z = b0 * g.z + b1 * tr.z;
    o.w = b0 * g.w + b1 * tr.w;
    ((float4*)out_geo)[gid] = o;
}

extern "C" void kernel_launch(void* const* d_in, const int* in_sizes, int n_in,
                              void* d_out, int out_size, void* d_ws, size_t ws_size,
                              hipStream_t stream) {
    const float* loc_feat = (const float*)d_in[0];
    const int* geo_src    = (const int*)d_in[1];
    const int* geo_dst    = (const int*)d_in[2];
    const int* trans_src  = (const int*)d_in[3];
    const int* trans_dst  = (const int*)d_in[4];
    const float* trans_w  = (const float*)d_in[5];
    const float* W1       = (const float*)d_in[6];
    const float* b1       = (const float*)d_in[7];
    const float* W2       = (const float*)d_in[8];
    float* out = (float*)d_out;

    // ws layout: [trans N*D f32][cnt2 2N i32][off2 2N i32][bsum 1024 i32]
    //            [geo_srcs E i32][trans_eid E i32][partials 25000 f32][beta 2 f32]
    // total ~35.3 MB
    float* trans    = (float*)d_ws;
    int*   cnt2     = (int*)(trans + (size_t)N_NODES * DIM);
    int*   off2     = cnt2 + TWO_N;
    int*   bsum     = off2 + TWO_N;
    int*   geo_srcs = bsum + 1024;
    int*   trans_eid= geo_srcs + E_EDGES;
    float* partials = (float*)(trans_eid + E_EDGES);
    float* beta     = partials + MLP_BLOCKS * 2;

    hipMemsetAsync(cnt2, 0, TWO_N * sizeof(int), stream);

    const int EB = (2 * E_EDGES + 255) / 256;   // 7813
    hist_kernel <<<EB, 256, 0, stream>>>(geo_dst, trans_dst, cnt2);
    scan1_kernel<<<SCAN_BLOCKS, 256, 0, stream>>>(cnt2, off2, bsum);
    scan2_kernel<<<1, 256, 0, stream>>>(bsum);
    scan3_kernel<<<SCAN_BLOCKS, 256, 0, stream>>>(off2, bsum);
    fill_kernel <<<EB, 256, 0, stream>>>(geo_src, geo_dst, trans_dst, off2, geo_srcs, trans_eid);

    gather_kernel<<<TWO_N / 4, 256, 0, stream>>>(loc_feat, cnt2, off2, geo_srcs, trans_eid,
                                                 trans_src, trans_w, out, trans);

    mlp_kernel<<<MLP_BLOCKS, 256, 0, stream>>>(out, trans, cnt2, W1, b1, W2, partials);
    beta_kernel<<<1, 256, 0, stream>>>(partials, beta);
    combine_kernel<<<(N_NODES * DIM / 4) / 256, 256, 0, stream>>>(out, trans, cnt2, beta);
}